// Round 1
// baseline (2083.602 us; speedup 1.0000x reference)
//
#include <hip/hip_runtime.h>
#include <math.h>

#define Bn 4
#define Tn 2048
#define En 1024
#define Hn 16
#define Dn 64

// C[M,N] = A[M,K] @ W[K,N] + bias[N]; BM=BN=64, BK=16, 256 threads, 4x4 microtile
__global__ __launch_bounds__(256) void gemm_bias_64x64(
    const float* __restrict__ A, const float* __restrict__ W,
    const float* __restrict__ bias, float* __restrict__ C,
    int M, int N, int K)
{
    __shared__ float As[16][68];   // [k][m], +4 pad keeps 16B alignment
    __shared__ float Bs[16][64];   // [k][n]

    const int t  = threadIdx.x;
    const int tx = t & 15;
    const int ty = t >> 4;
    const int block_row = blockIdx.y * 64;
    const int block_col = blockIdx.x * 64;

    const int a_row = t >> 2;          // 0..63
    const int a_col = (t & 3) << 2;    // 0,4,8,12
    const int b_row = t >> 4;          // 0..15
    const int b_col = (t & 15) << 2;   // 0..60

    float acc[4][4] = {};

    const float* Aptr = A + (size_t)(block_row + a_row) * K + a_col;
    const float* Wptr = W + (size_t)b_row * N + block_col + b_col;

    for (int k0 = 0; k0 < K; k0 += 16) {
        float4 av = *(const float4*)(Aptr + k0);
        float4 bv = *(const float4*)(Wptr + (size_t)k0 * N);
        As[a_col + 0][a_row] = av.x;
        As[a_col + 1][a_row] = av.y;
        As[a_col + 2][a_row] = av.z;
        As[a_col + 3][a_row] = av.w;
        *(float4*)&Bs[b_row][b_col] = bv;
        __syncthreads();
        #pragma unroll
        for (int k = 0; k < 16; ++k) {
            float4 af = *(const float4*)&As[k][ty << 2];
            float4 bf = *(const float4*)&Bs[k][tx << 2];
            float am[4] = {af.x, af.y, af.z, af.w};
            float bn[4] = {bf.x, bf.y, bf.z, bf.w};
            #pragma unroll
            for (int m = 0; m < 4; ++m)
                #pragma unroll
                for (int n = 0; n < 4; ++n)
                    acc[m][n] = fmaf(am[m], bn[n], acc[m][n]);
        }
        __syncthreads();
    }

    #pragma unroll
    for (int m = 0; m < 4; ++m) {
        const int row = block_row + (ty << 2) + m;
        const int col = block_col + (tx << 2);
        float4 ov;
        ov.x = acc[m][0] + bias[col + 0];
        ov.y = acc[m][1] + bias[col + 1];
        ov.z = acc[m][2] + bias[col + 2];
        ov.w = acc[m][3] + bias[col + 3];
        *(float4*)&C[(size_t)row * N + col] = ov;
    }
}

// Flash-style causal attention. Grid: (T/64 q-tiles, B*H). 256 threads.
// qkv layout: [B*T, 3E]; q at col h*D, k at E + h*D, v at 2E + h*D.
// Output y_attn: [B*T, E] with col h*D + d.
__global__ __launch_bounds__(256) void attn_flash(
    const float* __restrict__ qkv, float* __restrict__ yattn)
{
    __shared__ float Qt[64][68];   // [d][q_row]   (SCALE folded in)
    __shared__ float Kt[64][68];   // [d][k_col]
    __shared__ float Vs[64][68];   // [k_row][d]
    __shared__ float Pt[64][68];   // [k_col][q_row]

    const int t  = threadIdx.x;
    const int tx = t & 15;
    const int ty = t >> 4;
    const int bh = blockIdx.y;
    const int b  = bh >> 4;        // / H
    const int h  = bh & 15;        // % H
    const int q0 = blockIdx.x << 6;

    const size_t rs = 3 * En;
    const float* qbase = qkv + (size_t)(b * Tn) * rs + h * Dn;
    const float* kbase = qbase + En;
    const float* vbase = qbase + 2 * En;

    const int lc = (t & 15) << 2;  // d offset 0..60
    const int lr = t >> 4;         // row base 0..15

    #pragma unroll
    for (int i = 0; i < 4; ++i) {
        const int r = lr + (i << 4);
        float4 qv = *(const float4*)&qbase[(size_t)(q0 + r) * rs + lc];
        Qt[lc + 0][r] = qv.x * 0.125f;
        Qt[lc + 1][r] = qv.y * 0.125f;
        Qt[lc + 2][r] = qv.z * 0.125f;
        Qt[lc + 3][r] = qv.w * 0.125f;
    }

    float m_i[4], l_i[4], Oacc[4][4];
    #pragma unroll
    for (int m = 0; m < 4; ++m) {
        m_i[m] = -INFINITY;
        l_i[m] = 0.f;
        #pragma unroll
        for (int n = 0; n < 4; ++n) Oacc[m][n] = 0.f;
    }

    const int jmax = blockIdx.x;
    for (int j = 0; j <= jmax; ++j) {
        const int k0 = j << 6;
        __syncthreads();   // prev iteration's PV reads done before overwrite
        #pragma unroll
        for (int i = 0; i < 4; ++i) {
            const int r = lr + (i << 4);
            float4 kv = *(const float4*)&kbase[(size_t)(k0 + r) * rs + lc];
            Kt[lc + 0][r] = kv.x;
            Kt[lc + 1][r] = kv.y;
            Kt[lc + 2][r] = kv.z;
            Kt[lc + 3][r] = kv.w;
            *(float4*)&Vs[r][lc] = *(const float4*)&vbase[(size_t)(k0 + r) * rs + lc];
        }
        __syncthreads();

        // S(4x4 per thread): rows q0+ty*4+m, cols k0+tx*4+n
        float s[4][4] = {};
        #pragma unroll 8
        for (int d = 0; d < 64; ++d) {
            float4 af = *(const float4*)&Qt[d][ty << 2];
            float4 bf = *(const float4*)&Kt[d][tx << 2];
            float am[4] = {af.x, af.y, af.z, af.w};
            float bn[4] = {bf.x, bf.y, bf.z, bf.w};
            #pragma unroll
            for (int m = 0; m < 4; ++m)
                #pragma unroll
                for (int n = 0; n < 4; ++n)
                    s[m][n] = fmaf(am[m], bn[n], s[m][n]);
        }

        if (j == jmax) {   // diagonal tile: causal mask (q0 == k0)
            #pragma unroll
            for (int m = 0; m < 4; ++m) {
                const int row = (ty << 2) + m;
                #pragma unroll
                for (int n = 0; n < 4; ++n)
                    if (((tx << 2) + n) > row) s[m][n] = -INFINITY;
            }
        }

        // online softmax per row; row state replicated across the 16 tx lanes
        #pragma unroll
        for (int m = 0; m < 4; ++m) {
            float mx = fmaxf(fmaxf(s[m][0], s[m][1]), fmaxf(s[m][2], s[m][3]));
            mx = fmaxf(mx, __shfl_xor(mx, 1));
            mx = fmaxf(mx, __shfl_xor(mx, 2));
            mx = fmaxf(mx, __shfl_xor(mx, 4));
            mx = fmaxf(mx, __shfl_xor(mx, 8));
            const float m_new = fmaxf(m_i[m], mx);
            const float alpha = __expf(m_i[m] - m_new);
            float rsum = 0.f;
            #pragma unroll
            for (int n = 0; n < 4; ++n) {
                s[m][n] = __expf(s[m][n] - m_new);
                rsum += s[m][n];
            }
            rsum += __shfl_xor(rsum, 1);
            rsum += __shfl_xor(rsum, 2);
            rsum += __shfl_xor(rsum, 4);
            rsum += __shfl_xor(rsum, 8);
            l_i[m] = l_i[m] * alpha + rsum;
            m_i[m] = m_new;
            #pragma unroll
            for (int n = 0; n < 4; ++n) Oacc[m][n] *= alpha;
        }

        // P transposed into LDS: Pt[col][row]
        #pragma unroll
        for (int n = 0; n < 4; ++n) {
            float4 pv = {s[0][n], s[1][n], s[2][n], s[3][n]};
            *(float4*)&Pt[(tx << 2) + n][ty << 2] = pv;
        }
        __syncthreads();

        // O += P @ V : O[m][n] += sum_c P[row][c] * V[c][col]
        #pragma unroll 8
        for (int c = 0; c < 64; ++c) {
            float4 pf = *(const float4*)&Pt[c][ty << 2];
            float4 vf = *(const float4*)&Vs[c][tx << 2];
            float pm[4] = {pf.x, pf.y, pf.z, pf.w};
            float vn[4] = {vf.x, vf.y, vf.z, vf.w};
            #pragma unroll
            for (int m = 0; m < 4; ++m)
                #pragma unroll
                for (int n = 0; n < 4; ++n)
                    Oacc[m][n] = fmaf(pm[m], vn[n], Oacc[m][n]);
        }
    }

    #pragma unroll
    for (int m = 0; m < 4; ++m) {
        const float inv = 1.f / l_i[m];
        const int row = q0 + (ty << 2) + m;
        float4 ov = {Oacc[m][0] * inv, Oacc[m][1] * inv,
                     Oacc[m][2] * inv, Oacc[m][3] * inv};
        *(float4*)&yattn[(size_t)(b * Tn + row) * En + h * Dn + (tx << 2)] = ov;
    }
}

extern "C" void kernel_launch(void* const* d_in, const int* in_sizes, int n_in,
                              void* d_out, int out_size, void* d_ws, size_t ws_size,
                              hipStream_t stream)
{
    const float* x      = (const float*)d_in[0];
    const float* W_qkv  = (const float*)d_in[1];
    const float* b_qkv  = (const float*)d_in[2];
    const float* W_proj = (const float*)d_in[3];
    const float* b_proj = (const float*)d_in[4];
    float* out = (float*)d_out;

    const int M = Bn * Tn;                                   // 8192
    float* qkv   = (float*)d_ws;                             // [M, 3E] fp32
    float* yattn = (float*)((char*)d_ws + (size_t)M * 3 * En * sizeof(float)); // [M, E]

    dim3 blk(256);
    gemm_bias_64x64<<<dim3(3 * En / 64, M / 64), blk, 0, stream>>>(
        x, W_qkv, b_qkv, qkv, M, 3 * En, En);
    attn_flash<<<dim3(Tn / 64, Bn * Hn), blk, 0, stream>>>(qkv, yattn);
    gemm_bias_64x64<<<dim3(En / 64, M / 64), blk, 0, stream>>>(
        yattn, W_proj, b_proj, out, M, En, En);
}

// Round 2
// 481.135 us; speedup vs baseline: 4.3306x; 4.3306x over previous
//
#include <hip/hip_runtime.h>
#include <math.h>

#define Bn 4
#define Tn 2048
#define En 1024
#define Hn 16
#define Dn 64
#define RS (3 * En)

typedef __attribute__((ext_vector_type(8))) short bfrag;   // 8 bf16 in 4 VGPRs
typedef __attribute__((ext_vector_type(4))) float ffrag;   // 4 fp32 acc

__device__ __forceinline__ unsigned short f2bf(float f) {
    union { float f; unsigned int u; } v; v.f = f;
    unsigned int r = v.u + 0x7fffu + ((v.u >> 16) & 1u);   // RNE
    return (unsigned short)(r >> 16);
}

__device__ __forceinline__ void glds16(const unsigned short* g, unsigned short* l) {
    __builtin_amdgcn_global_load_lds(
        (const __attribute__((address_space(1))) unsigned int*)g,
        (__attribute__((address_space(3))) unsigned int*)l, 16, 0, 0);
}

// ---------------- fp32 -> bf16 elementwise ----------------
__global__ __launch_bounds__(256) void f2bf_vec(const float* __restrict__ in,
                                                unsigned short* __restrict__ out, int n) {
    int i = (blockIdx.x * 256 + threadIdx.x) * 4;
    if (i >= n) return;
    float4 v = *(const float4*)(in + i);
    ushort4 o;
    o.x = f2bf(v.x); o.y = f2bf(v.y); o.z = f2bf(v.z); o.w = f2bf(v.w);
    *(ushort4*)(out + i) = o;
}

// ---------------- W[K][N] fp32 -> Wt[N][K] bf16 ----------------
__global__ __launch_bounds__(256) void transpose_f2bf(const float* __restrict__ W,
                                                      unsigned short* __restrict__ Wt,
                                                      int K, int N) {
    __shared__ float s[64][65];
    const int kt = blockIdx.y * 64, nt = blockIdx.x * 64;
    const int tx = threadIdx.x & 15, ty = threadIdx.x >> 4;
#pragma unroll
    for (int i = 0; i < 4; ++i) {
        float4 v = *(const float4*)&W[(size_t)(kt + ty + i * 16) * N + nt + tx * 4];
        s[ty + i * 16][tx * 4 + 0] = v.x;
        s[ty + i * 16][tx * 4 + 1] = v.y;
        s[ty + i * 16][tx * 4 + 2] = v.z;
        s[ty + i * 16][tx * 4 + 3] = v.w;
    }
    __syncthreads();
#pragma unroll
    for (int i = 0; i < 4; ++i) {
        const int n = ty + i * 16;
        ushort4 o;
        o.x = f2bf(s[tx * 4 + 0][n]);
        o.y = f2bf(s[tx * 4 + 1][n]);
        o.z = f2bf(s[tx * 4 + 2][n]);
        o.w = f2bf(s[tx * 4 + 3][n]);
        *(ushort4*)&Wt[(size_t)(nt + n) * K + kt + tx * 4] = o;
    }
}

// ---------------- NT bf16 MFMA GEMM: C = A[M,K] @ Bt[N,K]^T + bias ----------------
// 128x128 tile, BK=32, 256 threads (4 waves 2x2, each 64x64).
// LDS in frag-order cells: cell[t16] holds lane l -> X[t16*16 + (l&15)][k0 + (l>>4)*8 ..+8]
template <int OUT_BF16>
__global__ __launch_bounds__(256) void gemm_nt_mfma(
    const unsigned short* __restrict__ A, const unsigned short* __restrict__ Bt,
    const float* __restrict__ bias, void* __restrict__ Cv,
    int M, int N, int K)
{
    __shared__ __attribute__((aligned(16))) unsigned short Asm[8][512];
    __shared__ __attribute__((aligned(16))) unsigned short Bsm[8][512];

    const int t = threadIdx.x;
    const int w = t >> 6, l = t & 63;
    const int wmt = (w & 1) * 4, wnt = (w >> 1) * 4;       // wave's 4x4 tile origin
    const int m0 = blockIdx.y * 128, n0 = blockIdx.x * 128;
    const int nl = l & 15, lk = (l >> 4) * 8;

    ffrag acc[4][4];
#pragma unroll
    for (int i = 0; i < 4; ++i)
#pragma unroll
        for (int j = 0; j < 4; ++j)
#pragma unroll
            for (int r = 0; r < 4; ++r) acc[i][j][r] = 0.f;

    const unsigned short* Ag = A + (size_t)(m0 + nl) * K + lk;
    const unsigned short* Bg = Bt + (size_t)(n0 + nl) * K + lk;

    for (int k0 = 0; k0 < K; k0 += 32) {
#pragma unroll
        for (int c = 0; c < 2; ++c) {
            const int mt = w * 2 + c;
            glds16(Ag + (size_t)mt * 16 * K + k0, &Asm[mt][0]);
            glds16(Bg + (size_t)mt * 16 * K + k0, &Bsm[mt][0]);
        }
        __syncthreads();
        bfrag af[4], bfr[4];
#pragma unroll
        for (int i = 0; i < 4; ++i) {
            af[i]  = *(const bfrag*)&Asm[wmt + i][l * 8];
            bfr[i] = *(const bfrag*)&Bsm[wnt + i][l * 8];
        }
#pragma unroll
        for (int i = 0; i < 4; ++i)
#pragma unroll
            for (int j = 0; j < 4; ++j)
                acc[i][j] = __builtin_amdgcn_mfma_f32_16x16x32_bf16(af[i], bfr[j], acc[i][j], 0, 0, 0);
        __syncthreads();
    }

    // epilogue: C/D layout col = l&15, row = (l>>4)*4 + reg
    const int orow = (l >> 4) * 4, ocol = l & 15;
#pragma unroll
    for (int i = 0; i < 4; ++i) {
        const int gm = m0 + (wmt + i) * 16 + orow;
#pragma unroll
        for (int j = 0; j < 4; ++j) {
            const int gn = n0 + (wnt + j) * 16 + ocol;
            const float bs = bias[gn];
#pragma unroll
            for (int r = 0; r < 4; ++r) {
                const float vv = acc[i][j][r] + bs;
                if (OUT_BF16)
                    ((unsigned short*)Cv)[(size_t)(gm + r) * N + gn] = f2bf(vv);
                else
                    ((float*)Cv)[(size_t)(gm + r) * N + gn] = vv;
            }
        }
    }
}

// ---------------- MFMA flash attention ----------------
// grid (T/128, B*H), 256 threads. Wave w owns 32 q-rows (2 m-tiles of 16).
// K-tile = 64. qkv bf16 [B*T][3E]. Output yattn bf16 [B*T][E].
__global__ __launch_bounds__(256) void attn_mfma(
    const unsigned short* __restrict__ qkv, unsigned short* __restrict__ yattn)
{
    __shared__ __attribute__((aligned(16))) unsigned short Ks[8][512];   // frag-order cells
    __shared__ __attribute__((aligned(16))) unsigned short Vt[64][72];   // [d][c]
    __shared__ __attribute__((aligned(16))) unsigned short Ps[4][32][72];// per-wave [m][c]

    const int t = threadIdx.x;
    const int w = t >> 6, l = t & 63;
    const int nl = l & 15, lq = l >> 4;
    const int b = blockIdx.y >> 4, h = blockIdx.y & 15;
    const int q0 = blockIdx.x * 128;
    const int rowb = q0 + w * 32;     // wave's min global q row

    const unsigned short* qbase = qkv + (size_t)(b * Tn) * RS + h * Dn;
    const unsigned short* kbase = qbase + En;
    const unsigned short* vbase = qbase + 2 * En;

    // Q A-frags: lane holds Q[rowb + mt*16 + nl][ks*32 + lq*8 ..+8]
    bfrag qf[2][2];
#pragma unroll
    for (int mt = 0; mt < 2; ++mt)
#pragma unroll
        for (int ks = 0; ks < 2; ++ks)
            qf[mt][ks] = *(const bfrag*)(qbase + (size_t)(rowb + mt * 16 + nl) * RS + ks * 32 + lq * 8);

    ffrag Oa[2][4];
    float m_i[2][4], l_i[2][4];
#pragma unroll
    for (int mt = 0; mt < 2; ++mt)
#pragma unroll
        for (int r = 0; r < 4; ++r) {
            m_i[mt][r] = -INFINITY; l_i[mt][r] = 0.f;
#pragma unroll
            for (int dt = 0; dt < 4; ++dt) Oa[mt][dt][r] = 0.f;
        }

    const int jmax = 2 * blockIdx.x + 1;
    for (int j = 0; j <= jmax; ++j) {
        const int k0 = j * 64;
        __syncthreads();   // prior PV reads of Ks/Vt done before restage

        // stage K (frag-order) and V (transposed) ; 2 rounds each
#pragma unroll
        for (int r = 0; r < 2; ++r) {
            const int sj8 = w + r * 4;                       // which 8-col group of d
            uint4 kd = *(const uint4*)(kbase + (size_t)(k0 + l) * RS + sj8 * 8);
            const int kseg = sj8 >> 2, lqw = sj8 & 3;
            *(uint4*)&Ks[lq * 2 + kseg][(lqw * 16 + nl) * 8] = kd;

            const int sd = w * 16 + r * 8;
            union { uint4 v; unsigned short s[8]; } u;
            u.v = *(const uint4*)(vbase + (size_t)(k0 + l) * RS + sd);
#pragma unroll
            for (int jj = 0; jj < 8; ++jj) Vt[sd + jj][l] = u.s[jj];
        }
        __syncthreads();

        bfrag kf[4][2];
#pragma unroll
        for (int nt = 0; nt < 4; ++nt)
#pragma unroll
            for (int ks = 0; ks < 2; ++ks)
                kf[nt][ks] = *(const bfrag*)&Ks[nt * 2 + ks][l * 8];

        const bool domask = (k0 + 63) > rowb;

#pragma unroll
        for (int mt = 0; mt < 2; ++mt) {
            ffrag s[4];
#pragma unroll
            for (int nt = 0; nt < 4; ++nt) {
#pragma unroll
                for (int r = 0; r < 4; ++r) s[nt][r] = 0.f;
                s[nt] = __builtin_amdgcn_mfma_f32_16x16x32_bf16(qf[mt][0], kf[nt][0], s[nt], 0, 0, 0);
                s[nt] = __builtin_amdgcn_mfma_f32_16x16x32_bf16(qf[mt][1], kf[nt][1], s[nt], 0, 0, 0);
#pragma unroll
                for (int r = 0; r < 4; ++r) s[nt][r] *= 0.125f;   // 1/sqrt(64)
            }
            if (domask) {
#pragma unroll
                for (int nt = 0; nt < 4; ++nt) {
                    const int kc = k0 + nt * 16 + nl;
#pragma unroll
                    for (int r = 0; r < 4; ++r) {
                        const int qr = rowb + mt * 16 + lq * 4 + r;
                        if (kc > qr) s[nt][r] = -INFINITY;
                    }
                }
            }
            // online softmax; rows live in 16-lane groups -> shfl_xor 1,2,4,8
#pragma unroll
            for (int r = 0; r < 4; ++r) {
                float mx = fmaxf(fmaxf(s[0][r], s[1][r]), fmaxf(s[2][r], s[3][r]));
                mx = fmaxf(mx, __shfl_xor(mx, 1));
                mx = fmaxf(mx, __shfl_xor(mx, 2));
                mx = fmaxf(mx, __shfl_xor(mx, 4));
                mx = fmaxf(mx, __shfl_xor(mx, 8));
                const float mnew = fmaxf(m_i[mt][r], mx);
                const float alpha = __expf(m_i[mt][r] - mnew);
                m_i[mt][r] = mnew;
                float rsum = 0.f;
#pragma unroll
                for (int nt = 0; nt < 4; ++nt) {
                    const float p = __expf(s[nt][r] - mnew);
                    s[nt][r] = p;
                    rsum += p;
                }
                rsum += __shfl_xor(rsum, 1);
                rsum += __shfl_xor(rsum, 2);
                rsum += __shfl_xor(rsum, 4);
                rsum += __shfl_xor(rsum, 8);
                l_i[mt][r] = l_i[mt][r] * alpha + rsum;
#pragma unroll
                for (int dt = 0; dt < 4; ++dt) Oa[mt][dt][r] *= alpha;
            }
            // P: C-layout -> LDS (A-layout round-trip), bf16
#pragma unroll
            for (int nt = 0; nt < 4; ++nt)
#pragma unroll
                for (int r = 0; r < 4; ++r)
                    Ps[w][mt * 16 + lq * 4 + r][nt * 16 + nl] = f2bf(s[nt][r]);
        }

        // PV: O[m][d] += P[m][c] V[c][d]   (same-wave LDS, no barrier needed)
#pragma unroll
        for (int cs = 0; cs < 2; ++cs) {
            bfrag pf0 = *(const bfrag*)&Ps[w][nl][cs * 32 + lq * 8];
            bfrag pf1 = *(const bfrag*)&Ps[w][16 + nl][cs * 32 + lq * 8];
#pragma unroll
            for (int dt = 0; dt < 4; ++dt) {
                bfrag vf = *(const bfrag*)&Vt[dt * 16 + nl][cs * 32 + lq * 8];
                Oa[0][dt] = __builtin_amdgcn_mfma_f32_16x16x32_bf16(pf0, vf, Oa[0][dt], 0, 0, 0);
                Oa[1][dt] = __builtin_amdgcn_mfma_f32_16x16x32_bf16(pf1, vf, Oa[1][dt], 0, 0, 0);
            }
        }
    }

    unsigned short* yb = yattn + (size_t)(b * Tn + rowb) * En + h * Dn;
#pragma unroll
    for (int mt = 0; mt < 2; ++mt)
#pragma unroll
        for (int r = 0; r < 4; ++r) {
            const float inv = 1.f / l_i[mt][r];
            const int row = mt * 16 + lq * 4 + r;
#pragma unroll
            for (int dt = 0; dt < 4; ++dt)
                yb[(size_t)row * En + dt * 16 + nl] = f2bf(Oa[mt][dt][r] * inv);
        }
}

extern "C" void kernel_launch(void* const* d_in, const int* in_sizes, int n_in,
                              void* d_out, int out_size, void* d_ws, size_t ws_size,
                              hipStream_t stream)
{
    const float* x      = (const float*)d_in[0];
    const float* W_qkv  = (const float*)d_in[1];
    const float* b_qkv  = (const float*)d_in[2];
    const float* W_proj = (const float*)d_in[3];
    const float* b_proj = (const float*)d_in[4];
    float* out = (float*)d_out;

    const int M = Bn * Tn;   // 8192
    char* ws = (char*)d_ws;
    unsigned short* xb   = (unsigned short*)ws; ws += (size_t)M * En * 2;
    unsigned short* Wqt  = (unsigned short*)ws; ws += (size_t)3 * En * En * 2;
    unsigned short* Wpt  = (unsigned short*)ws; ws += (size_t)En * En * 2;
    unsigned short* qkvb = (unsigned short*)ws; ws += (size_t)M * 3 * En * 2;
    unsigned short* yb   = (unsigned short*)ws;

    f2bf_vec<<<(M * En / 4 + 255) / 256, 256, 0, stream>>>(x, xb, M * En);
    transpose_f2bf<<<dim3(3 * En / 64, En / 64), 256, 0, stream>>>(W_qkv, Wqt, En, 3 * En);
    transpose_f2bf<<<dim3(En / 64, En / 64), 256, 0, stream>>>(W_proj, Wpt, En, En);

    gemm_nt_mfma<1><<<dim3(3 * En / 128, M / 128), 256, 0, stream>>>(
        xb, Wqt, b_qkv, qkvb, M, 3 * En, En);

    attn_mfma<<<dim3(Tn / 128, Bn * Hn), 256, 0, stream>>>(qkvb, yb);

    gemm_nt_mfma<0><<<dim3(En / 128, M / 128), 256, 0, stream>>>(
        yb, Wpt, b_proj, out, M, En, En);
}

// Round 3
// 368.372 us; speedup vs baseline: 5.6562x; 1.3061x over previous
//
#include <hip/hip_runtime.h>
#include <math.h>

#define Bn 4
#define Tn 2048
#define En 1024
#define Hn 16
#define Dn 64
#define RS (3 * En)
#define QSCALE 0.18033688f   // (1/sqrt(64)) * log2(e)  -> softmax in exp2 domain

typedef __attribute__((ext_vector_type(8))) short bfrag;   // 8 bf16 in 4 VGPRs
typedef __attribute__((ext_vector_type(4))) float ffrag;   // 4 fp32 acc

__device__ __forceinline__ unsigned short f2bf(float f) {
    union { float f; unsigned int u; } v; v.f = f;
    unsigned int r = v.u + 0x7fffu + ((v.u >> 16) & 1u);   // RNE
    return (unsigned short)(r >> 16);
}
__device__ __forceinline__ unsigned short f2bf_fast(float f) {  // P in [0,1], no NaN
    union { float f; unsigned int u; } v; v.f = f;
    return (unsigned short)((v.u + 0x8000u) >> 16);
}

__device__ __forceinline__ void glds16(const unsigned short* g, unsigned short* l) {
    __builtin_amdgcn_global_load_lds(
        (const __attribute__((address_space(1))) unsigned int*)g,
        (__attribute__((address_space(3))) unsigned int*)l, 16, 0, 0);
}

// ---- DPP 16-lane row reductions (VALU pipe, no LDS) ----
template <int CTRL>
__device__ __forceinline__ float dpp_max_step(float x) {
    int s = __builtin_amdgcn_update_dpp(0, __builtin_bit_cast(int, x), CTRL, 0xF, 0xF, true);
    return fmaxf(x, __builtin_bit_cast(float, s));
}
template <int CTRL>
__device__ __forceinline__ float dpp_add_step(float x) {
    int s = __builtin_amdgcn_update_dpp(0, __builtin_bit_cast(int, x), CTRL, 0xF, 0xF, true);
    return x + __builtin_bit_cast(float, s);
}
__device__ __forceinline__ float rowmax16(float x) {
    x = dpp_max_step<0xB1>(x);    // quad_perm xor1
    x = dpp_max_step<0x4E>(x);    // quad_perm xor2
    x = dpp_max_step<0x141>(x);   // row_half_mirror
    x = dpp_max_step<0x140>(x);   // row_mirror
    return x;
}
__device__ __forceinline__ float rowsum16(float x) {
    x = dpp_add_step<0xB1>(x);
    x = dpp_add_step<0x4E>(x);
    x = dpp_add_step<0x141>(x);
    x = dpp_add_step<0x140>(x);
    return x;
}

// ---------------- fp32 -> bf16 elementwise ----------------
__global__ __launch_bounds__(256) void f2bf_vec(const float* __restrict__ in,
                                                unsigned short* __restrict__ out, int n) {
    int i = (blockIdx.x * 256 + threadIdx.x) * 4;
    if (i >= n) return;
    float4 v = *(const float4*)(in + i);
    ushort4 o;
    o.x = f2bf(v.x); o.y = f2bf(v.y); o.z = f2bf(v.z); o.w = f2bf(v.w);
    *(ushort4*)(out + i) = o;
}

// ---------------- W[K][N] fp32 -> Wt[N][K] bf16 ----------------
__global__ __launch_bounds__(256) void transpose_f2bf(const float* __restrict__ W,
                                                      unsigned short* __restrict__ Wt,
                                                      int K, int N) {
    __shared__ float s[64][65];
    const int kt = blockIdx.y * 64, nt = blockIdx.x * 64;
    const int tx = threadIdx.x & 15, ty = threadIdx.x >> 4;
#pragma unroll
    for (int i = 0; i < 4; ++i) {
        float4 v = *(const float4*)&W[(size_t)(kt + ty + i * 16) * N + nt + tx * 4];
        s[ty + i * 16][tx * 4 + 0] = v.x;
        s[ty + i * 16][tx * 4 + 1] = v.y;
        s[ty + i * 16][tx * 4 + 2] = v.z;
        s[ty + i * 16][tx * 4 + 3] = v.w;
    }
    __syncthreads();
#pragma unroll
    for (int i = 0; i < 4; ++i) {
        const int n = ty + i * 16;
        ushort4 o;
        o.x = f2bf(s[tx * 4 + 0][n]);
        o.y = f2bf(s[tx * 4 + 1][n]);
        o.z = f2bf(s[tx * 4 + 2][n]);
        o.w = f2bf(s[tx * 4 + 3][n]);
        *(ushort4*)&Wt[(size_t)(nt + n) * K + kt + tx * 4] = o;
    }
}

// ---------------- NT bf16 MFMA GEMM: C = A[M,K] @ Bt[N,K]^T + bias ----------------
// Columns gn < qcols get scaled by QSCALE (q pre-scaling for exp2-domain softmax).
template <int OUT_BF16>
__global__ __launch_bounds__(256) void gemm_nt_mfma(
    const unsigned short* __restrict__ A, const unsigned short* __restrict__ Bt,
    const float* __restrict__ bias, void* __restrict__ Cv,
    int M, int N, int K, int qcols)
{
    __shared__ __attribute__((aligned(16))) unsigned short Asm[8][512];
    __shared__ __attribute__((aligned(16))) unsigned short Bsm[8][512];

    const int t = threadIdx.x;
    const int w = t >> 6, l = t & 63;
    const int wmt = (w & 1) * 4, wnt = (w >> 1) * 4;
    const int m0 = blockIdx.y * 128, n0 = blockIdx.x * 128;
    const int nl = l & 15, lk = (l >> 4) * 8;

    ffrag acc[4][4];
#pragma unroll
    for (int i = 0; i < 4; ++i)
#pragma unroll
        for (int j = 0; j < 4; ++j)
#pragma unroll
            for (int r = 0; r < 4; ++r) acc[i][j][r] = 0.f;

    const unsigned short* Ag = A + (size_t)(m0 + nl) * K + lk;
    const unsigned short* Bg = Bt + (size_t)(n0 + nl) * K + lk;

    for (int k0 = 0; k0 < K; k0 += 32) {
#pragma unroll
        for (int c = 0; c < 2; ++c) {
            const int mt = w * 2 + c;
            glds16(Ag + (size_t)mt * 16 * K + k0, &Asm[mt][0]);
            glds16(Bg + (size_t)mt * 16 * K + k0, &Bsm[mt][0]);
        }
        __syncthreads();
        bfrag af[4], bfr[4];
#pragma unroll
        for (int i = 0; i < 4; ++i) {
            af[i]  = *(const bfrag*)&Asm[wmt + i][l * 8];
            bfr[i] = *(const bfrag*)&Bsm[wnt + i][l * 8];
        }
#pragma unroll
        for (int i = 0; i < 4; ++i)
#pragma unroll
            for (int j = 0; j < 4; ++j)
                acc[i][j] = __builtin_amdgcn_mfma_f32_16x16x32_bf16(af[i], bfr[j], acc[i][j], 0, 0, 0);
        __syncthreads();
    }

    const int orow = (l >> 4) * 4, ocol = l & 15;
#pragma unroll
    for (int i = 0; i < 4; ++i) {
        const int gm = m0 + (wmt + i) * 16 + orow;
#pragma unroll
        for (int j = 0; j < 4; ++j) {
            const int gn = n0 + (wnt + j) * 16 + ocol;
            const float bs = bias[gn];
            const float sc = (gn < qcols) ? QSCALE : 1.f;
#pragma unroll
            for (int r = 0; r < 4; ++r) {
                const float vv = (acc[i][j][r] + bs) * sc;
                if (OUT_BF16)
                    ((unsigned short*)Cv)[(size_t)(gm + r) * N + gn] = f2bf(vv);
                else
                    ((float*)Cv)[(size_t)(gm + r) * N + gn] = vv;
            }
        }
    }
}

// ---------------- MFMA flash attention, causal-paired ----------------
// grid (16, B*H), 256 threads. Block p does q-tiles {p, 31-p} (64 rows each):
// uniform 33 k-tiles per block. Wave w owns 16 q-rows. K-tile = 64.
// Scores arrive pre-scaled by SCALE*log2e -> softmax via exp2.
__global__ __launch_bounds__(256) void attn_mfma(
    const unsigned short* __restrict__ qkv, unsigned short* __restrict__ yattn)
{
    __shared__ __attribute__((aligned(16))) unsigned short KL[8][64][8];  // d-group g: [g][k-row][8]
    __shared__ __attribute__((aligned(16))) unsigned short Vt[64][72];    // [d][c]
    __shared__ __attribute__((aligned(16))) unsigned short Ps[4][16][72]; // per-wave P [m][c]

    const int t = threadIdx.x;
    const int w = t >> 6, l = t & 63;
    const int nl = l & 15, lq = l >> 4;
    const int b = blockIdx.y >> 4, h = blockIdx.y & 15;

    const unsigned short* qbase = qkv + (size_t)(b * Tn) * RS + h * Dn;
    const unsigned short* kbase = qbase + En;
    const unsigned short* vbase = qbase + 2 * En;

#pragma unroll 1
    for (int phase = 0; phase < 2; ++phase) {
        const int qt = phase ? (31 - blockIdx.x) : blockIdx.x;
        const int rowb = qt * 64 + w * 16;   // wave's 16 q-rows start here

        bfrag qf[2];
#pragma unroll
        for (int ks = 0; ks < 2; ++ks)
            qf[ks] = *(const bfrag*)(qbase + (size_t)(rowb + nl) * RS + ks * 32 + lq * 8);

        ffrag Oa[4];
        float m_i[4], l_i[4];
#pragma unroll
        for (int r = 0; r < 4; ++r) {
            m_i[r] = -INFINITY; l_i[r] = 0.f;
#pragma unroll
            for (int dt = 0; dt < 4; ++dt) Oa[dt][r] = 0.f;
        }

        for (int j = 0; j <= qt; ++j) {
            const int k0 = j * 64;
            __syncthreads();   // prior tile's PV reads done before restage
            // K: async direct-to-LDS, d-group cells
#pragma unroll
            for (int r = 0; r < 2; ++r) {
                const int g = w * 2 + r;
                glds16(kbase + (size_t)(k0 + l) * RS + g * 8, &KL[g][0][0]);
            }
            // V: transpose to d-major
#pragma unroll
            for (int r = 0; r < 2; ++r) {
                const int sd = w * 16 + r * 8;
                union { uint4 v; unsigned short s[8]; } u;
                u.v = *(const uint4*)(vbase + (size_t)(k0 + l) * RS + sd);
#pragma unroll
                for (int jj = 0; jj < 8; ++jj) Vt[sd + jj][l] = u.s[jj];
            }
            __syncthreads();

            bfrag kf[4][2];
#pragma unroll
            for (int nt = 0; nt < 4; ++nt)
#pragma unroll
                for (int ks = 0; ks < 2; ++ks)
                    kf[nt][ks] = *(const bfrag*)&KL[ks * 4 + lq][nt * 16 + nl][0];

            // S = Q~ K^T  (already in log2 domain)
            ffrag s[4];
#pragma unroll
            for (int nt = 0; nt < 4; ++nt) {
#pragma unroll
                for (int r = 0; r < 4; ++r) s[nt][r] = 0.f;
                s[nt] = __builtin_amdgcn_mfma_f32_16x16x32_bf16(qf[0], kf[nt][0], s[nt], 0, 0, 0);
                s[nt] = __builtin_amdgcn_mfma_f32_16x16x32_bf16(qf[1], kf[nt][1], s[nt], 0, 0, 0);
            }

            if (j == qt) {   // diagonal block: causal mask
#pragma unroll
                for (int nt = 0; nt < 4; ++nt) {
                    const int kc = k0 + nt * 16 + nl;
#pragma unroll
                    for (int r = 0; r < 4; ++r)
                        if (kc > rowb + lq * 4 + r) s[nt][r] = -INFINITY;
                }
            }

            // online softmax (exp2 domain); row = 16 consecutive lanes (same lq)
#pragma unroll
            for (int r = 0; r < 4; ++r) {
                float mx = fmaxf(fmaxf(s[0][r], s[1][r]), fmaxf(s[2][r], s[3][r]));
                mx = rowmax16(mx);
                const float mnew = fmaxf(m_i[r], mx);
                const float alpha = __builtin_amdgcn_exp2f(m_i[r] - mnew);
                m_i[r] = mnew;
                float p0 = __builtin_amdgcn_exp2f(s[0][r] - mnew);
                float p1 = __builtin_amdgcn_exp2f(s[1][r] - mnew);
                float p2 = __builtin_amdgcn_exp2f(s[2][r] - mnew);
                float p3 = __builtin_amdgcn_exp2f(s[3][r] - mnew);
                l_i[r] = l_i[r] * alpha + ((p0 + p1) + (p2 + p3));   // per-lane partial
#pragma unroll
                for (int dt = 0; dt < 4; ++dt) Oa[dt][r] *= alpha;
                const int prow = lq * 4 + r;
                Ps[w][prow][0 * 16 + nl] = f2bf_fast(p0);
                Ps[w][prow][1 * 16 + nl] = f2bf_fast(p1);
                Ps[w][prow][2 * 16 + nl] = f2bf_fast(p2);
                Ps[w][prow][3 * 16 + nl] = f2bf_fast(p3);
            }

            // PV (same-wave LDS round-trip; no barrier needed)
#pragma unroll
            for (int cs = 0; cs < 2; ++cs) {
                bfrag pf = *(const bfrag*)&Ps[w][nl][cs * 32 + lq * 8];
#pragma unroll
                for (int dt = 0; dt < 4; ++dt) {
                    bfrag vf = *(const bfrag*)&Vt[dt * 16 + nl][cs * 32 + lq * 8];
                    Oa[dt] = __builtin_amdgcn_mfma_f32_16x16x32_bf16(pf, vf, Oa[dt], 0, 0, 0);
                }
            }
        }

        // epilogue: reduce l across the row once, normalize, store
        unsigned short* yb = yattn + (size_t)(b * Tn) * En + h * Dn;
#pragma unroll
        for (int r = 0; r < 4; ++r) {
            const float lr = rowsum16(l_i[r]);
            const float inv = 1.f / lr;
            const int row = rowb + lq * 4 + r;
#pragma unroll
            for (int dt = 0; dt < 4; ++dt)
                yb[(size_t)row * En + dt * 16 + nl] = f2bf(Oa[dt][r] * inv);
        }
    }
}

extern "C" void kernel_launch(void* const* d_in, const int* in_sizes, int n_in,
                              void* d_out, int out_size, void* d_ws, size_t ws_size,
                              hipStream_t stream)
{
    const float* x      = (const float*)d_in[0];
    const float* W_qkv  = (const float*)d_in[1];
    const float* b_qkv  = (const float*)d_in[2];
    const float* W_proj = (const float*)d_in[3];
    const float* b_proj = (const float*)d_in[4];
    float* out = (float*)d_out;

    const int M = Bn * Tn;   // 8192
    char* ws = (char*)d_ws;
    unsigned short* xb   = (unsigned short*)ws; ws += (size_t)M * En * 2;
    unsigned short* Wqt  = (unsigned short*)ws; ws += (size_t)3 * En * En * 2;
    unsigned short* Wpt  = (unsigned short*)ws; ws += (size_t)En * En * 2;
    unsigned short* qkvb = (unsigned short*)ws; ws += (size_t)M * 3 * En * 2;
    unsigned short* yb   = (unsigned short*)ws;

    f2bf_vec<<<(M * En / 4 + 255) / 256, 256, 0, stream>>>(x, xb, M * En);
    transpose_f2bf<<<dim3(3 * En / 64, En / 64), 256, 0, stream>>>(W_qkv, Wqt, En, 3 * En);
    transpose_f2bf<<<dim3(En / 64, En / 64), 256, 0, stream>>>(W_proj, Wpt, En, En);

    gemm_nt_mfma<1><<<dim3(3 * En / 128, M / 128), 256, 0, stream>>>(
        xb, Wqt, b_qkv, qkvb, M, 3 * En, En, En);

    attn_mfma<<<dim3(16, Bn * Hn), 256, 0, stream>>>(qkvb, yb);

    gemm_nt_mfma<0><<<dim3(En / 128, M / 128), 256, 0, stream>>>(
        yb, Wpt, b_proj, out, M, En, En, 0);
}

// Round 4
// 340.740 us; speedup vs baseline: 6.1149x; 1.0811x over previous
//
#include <hip/hip_runtime.h>
#include <math.h>

#define Bn 4
#define Tn 2048
#define En 1024
#define Hn 16
#define Dn 64
#define QSCALE 0.18033688f   // (1/sqrt(64)) * log2(e)  -> softmax in exp2 domain

typedef __attribute__((ext_vector_type(8))) short bfrag;   // 8 bf16 in 4 VGPRs
typedef __attribute__((ext_vector_type(4))) float ffrag;   // 4 fp32 acc

__device__ __forceinline__ unsigned short f2bf(float f) {
    union { float f; unsigned int u; } v; v.f = f;
    unsigned int r = v.u + 0x7fffu + ((v.u >> 16) & 1u);   // RNE
    return (unsigned short)(r >> 16);
}
__device__ __forceinline__ unsigned short f2bf_fast(float f) {  // P in [0,1], no NaN
    union { float f; unsigned int u; } v; v.f = f;
    return (unsigned short)((v.u + 0x8000u) >> 16);
}

__device__ __forceinline__ void glds16(const unsigned short* g, unsigned short* l) {
    __builtin_amdgcn_global_load_lds(
        (const __attribute__((address_space(1))) unsigned int*)g,
        (__attribute__((address_space(3))) unsigned int*)l, 16, 0, 0);
}

// ---- DPP 16-lane row reductions (VALU pipe, no LDS) ----
template <int CTRL>
__device__ __forceinline__ float dpp_max_step(float x) {
    int s = __builtin_amdgcn_update_dpp(0, __builtin_bit_cast(int, x), CTRL, 0xF, 0xF, true);
    return fmaxf(x, __builtin_bit_cast(float, s));
}
template <int CTRL>
__device__ __forceinline__ float dpp_add_step(float x) {
    int s = __builtin_amdgcn_update_dpp(0, __builtin_bit_cast(int, x), CTRL, 0xF, 0xF, true);
    return x + __builtin_bit_cast(float, s);
}
__device__ __forceinline__ float rowmax16(float x) {
    x = dpp_max_step<0xB1>(x);    // quad_perm xor1
    x = dpp_max_step<0x4E>(x);    // quad_perm xor2
    x = dpp_max_step<0x141>(x);   // row_half_mirror
    x = dpp_max_step<0x140>(x);   // row_mirror
    return x;
}
__device__ __forceinline__ float rowsum16(float x) {
    x = dpp_add_step<0xB1>(x);
    x = dpp_add_step<0x4E>(x);
    x = dpp_add_step<0x141>(x);
    x = dpp_add_step<0x140>(x);
    return x;
}

// ---------------- fp32 -> bf16 elementwise ----------------
__global__ __launch_bounds__(256) void f2bf_vec(const float* __restrict__ in,
                                                unsigned short* __restrict__ out, int n) {
    int i = (blockIdx.x * 256 + threadIdx.x) * 4;
    if (i >= n) return;
    float4 v = *(const float4*)(in + i);
    ushort4 o;
    o.x = f2bf(v.x); o.y = f2bf(v.y); o.z = f2bf(v.z); o.w = f2bf(v.w);
    *(ushort4*)(out + i) = o;
}

// ---------------- W[K][N] fp32 -> Wt[N][K] bf16 ----------------
__global__ __launch_bounds__(256) void transpose_f2bf(const float* __restrict__ W,
                                                      unsigned short* __restrict__ Wt,
                                                      int K, int N) {
    __shared__ float s[64][65];
    const int kt = blockIdx.y * 64, nt = blockIdx.x * 64;
    const int tx = threadIdx.x & 15, ty = threadIdx.x >> 4;
#pragma unroll
    for (int i = 0; i < 4; ++i) {
        float4 v = *(const float4*)&W[(size_t)(kt + ty + i * 16) * N + nt + tx * 4];
        s[ty + i * 16][tx * 4 + 0] = v.x;
        s[ty + i * 16][tx * 4 + 1] = v.y;
        s[ty + i * 16][tx * 4 + 2] = v.z;
        s[ty + i * 16][tx * 4 + 3] = v.w;
    }
    __syncthreads();
#pragma unroll
    for (int i = 0; i < 4; ++i) {
        const int n = ty + i * 16;
        ushort4 o;
        o.x = f2bf(s[tx * 4 + 0][n]);
        o.y = f2bf(s[tx * 4 + 1][n]);
        o.z = f2bf(s[tx * 4 + 2][n]);
        o.w = f2bf(s[tx * 4 + 3][n]);
        *(ushort4*)&Wt[(size_t)(nt + n) * K + kt + tx * 4] = o;
    }
}

// ---------------- NT bf16 MFMA GEMM: C = A[M,K] @ Bt[N,K]^T + bias ----------------
// qcols>0: columns gn<qcols scaled by QSCALE (q pre-scale for exp2 softmax).
// VSPLIT: columns gn>=vstart are V -> stored transposed into vt[(bh*Dn+dd)][Tn];
//         other columns go to C (row stride ldc) only when gn < vstart.
template <int OUT_BF16, int VSPLIT>
__global__ __launch_bounds__(256) void gemm_nt_mfma(
    const unsigned short* __restrict__ A, const unsigned short* __restrict__ Bt,
    const float* __restrict__ bias, void* __restrict__ Cv, int ldc,
    unsigned short* __restrict__ vt, int vstart,
    int M, int N, int K, int qcols)
{
    __shared__ __attribute__((aligned(16))) unsigned short Asm[8][512];
    __shared__ __attribute__((aligned(16))) unsigned short Bsm[8][512];

    const int t = threadIdx.x;
    const int w = t >> 6, l = t & 63;
    const int wmt = (w & 1) * 4, wnt = (w >> 1) * 4;
    const int m0 = blockIdx.y * 128, n0 = blockIdx.x * 128;
    const int nl = l & 15, lk = (l >> 4) * 8;

    ffrag acc[4][4];
#pragma unroll
    for (int i = 0; i < 4; ++i)
#pragma unroll
        for (int j = 0; j < 4; ++j)
#pragma unroll
            for (int r = 0; r < 4; ++r) acc[i][j][r] = 0.f;

    const unsigned short* Ag = A + (size_t)(m0 + nl) * K + lk;
    const unsigned short* Bg = Bt + (size_t)(n0 + nl) * K + lk;

    for (int k0 = 0; k0 < K; k0 += 32) {
#pragma unroll
        for (int c = 0; c < 2; ++c) {
            const int mt = w * 2 + c;
            glds16(Ag + (size_t)mt * 16 * K + k0, &Asm[mt][0]);
            glds16(Bg + (size_t)mt * 16 * K + k0, &Bsm[mt][0]);
        }
        __syncthreads();
        bfrag af[4], bfr[4];
#pragma unroll
        for (int i = 0; i < 4; ++i) {
            af[i]  = *(const bfrag*)&Asm[wmt + i][l * 8];
            bfr[i] = *(const bfrag*)&Bsm[wnt + i][l * 8];
        }
#pragma unroll
        for (int i = 0; i < 4; ++i)
#pragma unroll
            for (int j = 0; j < 4; ++j)
                acc[i][j] = __builtin_amdgcn_mfma_f32_16x16x32_bf16(af[i], bfr[j], acc[i][j], 0, 0, 0);
        __syncthreads();
    }

    const int orow = (l >> 4) * 4, ocol = l & 15;
#pragma unroll
    for (int i = 0; i < 4; ++i) {
        const int gm = m0 + (wmt + i) * 16 + orow;
#pragma unroll
        for (int j = 0; j < 4; ++j) {
            const int gn = n0 + (wnt + j) * 16 + ocol;
            const float bs = bias[gn];
            if (VSPLIT && gn >= vstart) {
                // V column -> transposed store: vt[(h*Dn+dd)... per (b,h)]
                const int vc = gn - vstart;
                const int b  = gm / Tn;
                const int tt = gm - b * Tn;
                ushort4 o;
                o.x = f2bf(acc[i][j][0] + bs);
                o.y = f2bf(acc[i][j][1] + bs);
                o.z = f2bf(acc[i][j][2] + bs);
                o.w = f2bf(acc[i][j][3] + bs);
                *(ushort4*)&vt[(size_t)(b * Hn * Dn + vc) * Tn + tt] = o;
            } else {
                const float sc = (qcols && gn < qcols) ? QSCALE : 1.f;
#pragma unroll
                for (int r = 0; r < 4; ++r) {
                    const float vv = (acc[i][j][r] + bs) * sc;
                    if (OUT_BF16)
                        ((unsigned short*)Cv)[(size_t)(gm + r) * ldc + gn] = f2bf(vv);
                    else
                        ((float*)Cv)[(size_t)(gm + r) * ldc + gn] = vv;
                }
            }
        }
    }
}

// ---------------- MFMA flash attention, causal-paired, K-tile 128 ----------------
// grid 1024 blocks as (16,64); flat id -> bh = flat&63 (XCD-local K/V reuse),
// p = flat>>6. Block handles q-tiles {p, 31-p} (64 rows each): uniform 17 k-tiles.
// Wave owns 16 q-rows. K and V staged via global_load_lds into fragment-order
// 1KB cells (identity lane mapping -> conflict-free b128 frag reads).
__global__ __launch_bounds__(256) void attn_mfma(
    const unsigned short* __restrict__ qkv,   // [B*T][2E]  Q|K, Q pre-scaled
    const unsigned short* __restrict__ vtg,   // [B*H*D][T] V transposed
    unsigned short* __restrict__ yattn)       // [B*T][E]
{
    __shared__ __attribute__((aligned(16))) unsigned short KL[16][512]; // cell(nt,ks)=KL[nt*2+ks]
    __shared__ __attribute__((aligned(16))) unsigned short VL[16][512]; // cell(dt,cs)=VL[dt*4+cs]
    __shared__ __attribute__((aligned(16))) unsigned short Ps[4][16][136];

    const int t = threadIdx.x;
    const int w = t >> 6, l = t & 63;
    const int nl = l & 15, lq = l >> 4;
    const int flat = blockIdx.x + (blockIdx.y << 4);
    const int bh = flat & 63;
    const int p  = flat >> 6;
    const int b = bh >> 4, h = bh & 15;

    const unsigned short* qbase = qkv + (size_t)(b * Tn) * (2 * En) + h * Dn;
    const unsigned short* kbase = qbase + En;
    const unsigned short* vbase = vtg + (size_t)(bh * Dn) * Tn;

#pragma unroll 1
    for (int phase = 0; phase < 2; ++phase) {
        const int qt = phase ? (31 - p) : p;
        const int rowb = qt * 64 + w * 16;
        const int jmax = qt >> 1;

        bfrag qf[2];
#pragma unroll
        for (int ks = 0; ks < 2; ++ks)
            qf[ks] = *(const bfrag*)(qbase + (size_t)(rowb + nl) * (2 * En) + ks * 32 + lq * 8);

        ffrag Oa[4];
        float m_i[4], l_i[4];
#pragma unroll
        for (int r = 0; r < 4; ++r) {
            m_i[r] = -INFINITY; l_i[r] = 0.f;
#pragma unroll
            for (int dt = 0; dt < 4; ++dt) Oa[dt][r] = 0.f;
        }

        for (int j = 0; j <= jmax; ++j) {
            const int k0 = j << 7;
            __syncthreads();   // prior tile's frag reads done before restage
#pragma unroll
            for (int r = 0; r < 4; ++r) {
                const int c4 = w * 4 + r;
                const int knt = c4 >> 1, kks = c4 & 1;
                glds16(kbase + (size_t)(k0 + knt * 16 + nl) * (2 * En) + kks * 32 + lq * 8,
                       &KL[c4][0]);
                const int vdt = c4 >> 2, vcs = c4 & 3;
                glds16(vbase + (size_t)(vdt * 16 + nl) * Tn + k0 + vcs * 32 + lq * 8,
                       &VL[c4][0]);
            }
            __syncthreads();

            // S = Q~ K^T (exp2 domain, pre-scaled)
            ffrag s[8];
#pragma unroll
            for (int nt = 0; nt < 8; ++nt) {
                bfrag ka = *(const bfrag*)&KL[nt * 2 + 0][l * 8];
                bfrag kb = *(const bfrag*)&KL[nt * 2 + 1][l * 8];
                ffrag z;
#pragma unroll
                for (int r = 0; r < 4; ++r) z[r] = 0.f;
                z = __builtin_amdgcn_mfma_f32_16x16x32_bf16(qf[0], ka, z, 0, 0, 0);
                s[nt] = __builtin_amdgcn_mfma_f32_16x16x32_bf16(qf[1], kb, z, 0, 0, 0);
            }

            if (j == jmax) {   // tile containing the diagonal: causal mask
#pragma unroll
                for (int nt = 0; nt < 8; ++nt) {
                    const int kc = k0 + nt * 16 + nl;
#pragma unroll
                    for (int r = 0; r < 4; ++r)
                        if (kc > rowb + lq * 4 + r) s[nt][r] = -INFINITY;
                }
            }

            // online softmax per row (rows = 16-lane groups)
#pragma unroll
            for (int r = 0; r < 4; ++r) {
                float mx = fmaxf(fmaxf(fmaxf(s[0][r], s[1][r]), fmaxf(s[2][r], s[3][r])),
                                 fmaxf(fmaxf(s[4][r], s[5][r]), fmaxf(s[6][r], s[7][r])));
                mx = rowmax16(mx);
                const float mnew = fmaxf(m_i[r], mx);
                const float alpha = __builtin_amdgcn_exp2f(m_i[r] - mnew);
                m_i[r] = mnew;
                float pv[8], rsum = 0.f;
#pragma unroll
                for (int nt = 0; nt < 8; ++nt) {
                    pv[nt] = __builtin_amdgcn_exp2f(s[nt][r] - mnew);
                    rsum += pv[nt];
                }
                l_i[r] = l_i[r] * alpha + rsum;
#pragma unroll
                for (int dt = 0; dt < 4; ++dt) Oa[dt][r] *= alpha;
                const int prow = lq * 4 + r;
#pragma unroll
                for (int nt = 0; nt < 8; ++nt)
                    Ps[w][prow][nt * 16 + nl] = f2bf_fast(pv[nt]);
            }

            // PV (wave-private Ps; DS pipe is in-order per wave)
#pragma unroll
            for (int cs = 0; cs < 4; ++cs) {
                bfrag pf = *(const bfrag*)&Ps[w][nl][cs * 32 + lq * 8];
#pragma unroll
                for (int dt = 0; dt < 4; ++dt) {
                    bfrag vf = *(const bfrag*)&VL[dt * 4 + cs][l * 8];
                    Oa[dt] = __builtin_amdgcn_mfma_f32_16x16x32_bf16(pf, vf, Oa[dt], 0, 0, 0);
                }
            }
        }

        unsigned short* yb = yattn + (size_t)(b * Tn) * En + h * Dn;
#pragma unroll
        for (int r = 0; r < 4; ++r) {
            const float lr = rowsum16(l_i[r]);
            const float inv = 1.f / lr;
            const int row = rowb + lq * 4 + r;
#pragma unroll
            for (int dt = 0; dt < 4; ++dt)
                yb[(size_t)row * En + dt * 16 + nl] = f2bf(Oa[dt][r] * inv);
        }
    }
}

extern "C" void kernel_launch(void* const* d_in, const int* in_sizes, int n_in,
                              void* d_out, int out_size, void* d_ws, size_t ws_size,
                              hipStream_t stream)
{
    const float* x      = (const float*)d_in[0];
    const float* W_qkv  = (const float*)d_in[1];
    const float* b_qkv  = (const float*)d_in[2];
    const float* W_proj = (const float*)d_in[3];
    const float* b_proj = (const float*)d_in[4];
    float* out = (float*)d_out;

    const int M = Bn * Tn;   // 8192
    char* ws = (char*)d_ws;
    unsigned short* xb   = (unsigned short*)ws; ws += (size_t)M * En * 2;
    unsigned short* Wqt  = (unsigned short*)ws; ws += (size_t)3 * En * En * 2;
    unsigned short* Wpt  = (unsigned short*)ws; ws += (size_t)En * En * 2;
    unsigned short* qkb  = (unsigned short*)ws; ws += (size_t)M * 2 * En * 2;   // Q|K
    unsigned short* vtg  = (unsigned short*)ws; ws += (size_t)M * En * 2;       // V^T per head
    unsigned short* yb   = (unsigned short*)ws;

    f2bf_vec<<<(M * En / 4 + 255) / 256, 256, 0, stream>>>(x, xb, M * En);
    transpose_f2bf<<<dim3(3 * En / 64, En / 64), 256, 0, stream>>>(W_qkv, Wqt, En, 3 * En);
    transpose_f2bf<<<dim3(En / 64, En / 64), 256, 0, stream>>>(W_proj, Wpt, En, En);

    gemm_nt_mfma<1, 1><<<dim3(3 * En / 128, M / 128), 256, 0, stream>>>(
        xb, Wqt, b_qkv, qkb, 2 * En, vtg, 2 * En, M, 3 * En, En, En);

    attn_mfma<<<dim3(16, Bn * Hn), 256, 0, stream>>>(qkb, vtg, yb);

    gemm_nt_mfma<0, 0><<<dim3(En / 128, M / 128), 256, 0, stream>>>(
        yb, Wpt, b_proj, out, En, nullptr, 1 << 30, M, En, En, 0);
}

// Round 5
// 310.743 us; speedup vs baseline: 6.7052x; 1.0965x over previous
//
#include <hip/hip_runtime.h>
#include <math.h>

#define Bn 4
#define Tn 2048
#define En 1024
#define Hn 16
#define Dn 64
#define RS2 (2 * En)
#define QSCALE 0.18033688f   // (1/sqrt(64)) * log2(e)  -> softmax in exp2 domain
#define SMAX 16.0f           // static softmax max (log2 domain); scores bounded << 16

typedef __attribute__((ext_vector_type(8))) short bfrag;   // 8 bf16 in 4 VGPRs
typedef __attribute__((ext_vector_type(4))) float ffrag;   // 4 fp32 acc

__device__ __forceinline__ unsigned short f2bf(float f) {
    union { float f; unsigned int u; } v; v.f = f;
    unsigned int r = v.u + 0x7fffu + ((v.u >> 16) & 1u);   // RNE
    return (unsigned short)(r >> 16);
}
__device__ __forceinline__ unsigned short f2bf_fast(float f) {  // positive, no NaN
    union { float f; unsigned int u; } v; v.f = f;
    return (unsigned short)((v.u + 0x8000u) >> 16);
}

__device__ __forceinline__ void glds16(const unsigned short* g, unsigned short* l) {
    __builtin_amdgcn_global_load_lds(
        (const __attribute__((address_space(1))) unsigned int*)g,
        (__attribute__((address_space(3))) unsigned int*)l, 16, 0, 0);
}

// ---- DPP 16-lane row sum (epilogue only) ----
template <int CTRL>
__device__ __forceinline__ float dpp_add_step(float x) {
    int s = __builtin_amdgcn_update_dpp(0, __builtin_bit_cast(int, x), CTRL, 0xF, 0xF, true);
    return x + __builtin_bit_cast(float, s);
}
__device__ __forceinline__ float rowsum16(float x) {
    x = dpp_add_step<0xB1>(x);    // quad_perm xor1
    x = dpp_add_step<0x4E>(x);    // quad_perm xor2
    x = dpp_add_step<0x141>(x);   // row_half_mirror
    x = dpp_add_step<0x140>(x);   // row_mirror
    return x;
}

// ---------------- fp32 -> bf16 elementwise ----------------
__global__ __launch_bounds__(256) void f2bf_vec(const float* __restrict__ in,
                                                unsigned short* __restrict__ out, int n) {
    int i = (blockIdx.x * 256 + threadIdx.x) * 4;
    if (i >= n) return;
    float4 v = *(const float4*)(in + i);
    ushort4 o;
    o.x = f2bf(v.x); o.y = f2bf(v.y); o.z = f2bf(v.z); o.w = f2bf(v.w);
    *(ushort4*)(out + i) = o;
}

// ---------------- W[K][N] fp32 -> Wt[N][K] bf16 ----------------
__global__ __launch_bounds__(256) void transpose_f2bf(const float* __restrict__ W,
                                                      unsigned short* __restrict__ Wt,
                                                      int K, int N) {
    __shared__ float s[64][65];
    const int kt = blockIdx.y * 64, nt = blockIdx.x * 64;
    const int tx = threadIdx.x & 15, ty = threadIdx.x >> 4;
#pragma unroll
    for (int i = 0; i < 4; ++i) {
        float4 v = *(const float4*)&W[(size_t)(kt + ty + i * 16) * N + nt + tx * 4];
        s[ty + i * 16][tx * 4 + 0] = v.x;
        s[ty + i * 16][tx * 4 + 1] = v.y;
        s[ty + i * 16][tx * 4 + 2] = v.z;
        s[ty + i * 16][tx * 4 + 3] = v.w;
    }
    __syncthreads();
#pragma unroll
    for (int i = 0; i < 4; ++i) {
        const int n = ty + i * 16;
        ushort4 o;
        o.x = f2bf(s[tx * 4 + 0][n]);
        o.y = f2bf(s[tx * 4 + 1][n]);
        o.z = f2bf(s[tx * 4 + 2][n]);
        o.w = f2bf(s[tx * 4 + 3][n]);
        *(ushort4*)&Wt[(size_t)(nt + n) * K + kt + tx * 4] = o;
    }
}

// ---------------- NT bf16 MFMA GEMM: C = A[M,K] @ Bt[N,K]^T + bias ----------------
// qcols>0: columns gn<qcols scaled by QSCALE (q pre-scale for exp2 softmax).
// VSPLIT: columns gn>=vstart are V -> stored transposed into vt[(bh*Dn+dd)][Tn].
template <int OUT_BF16, int VSPLIT>
__global__ __launch_bounds__(256) void gemm_nt_mfma(
    const unsigned short* __restrict__ A, const unsigned short* __restrict__ Bt,
    const float* __restrict__ bias, void* __restrict__ Cv, int ldc,
    unsigned short* __restrict__ vt, int vstart,
    int M, int N, int K, int qcols)
{
    __shared__ __attribute__((aligned(16))) unsigned short Asm[8][512];
    __shared__ __attribute__((aligned(16))) unsigned short Bsm[8][512];

    const int t = threadIdx.x;
    const int w = t >> 6, l = t & 63;
    const int wmt = (w & 1) * 4, wnt = (w >> 1) * 4;
    const int m0 = blockIdx.y * 128, n0 = blockIdx.x * 128;
    const int nl = l & 15, lk = (l >> 4) * 8;

    ffrag acc[4][4];
#pragma unroll
    for (int i = 0; i < 4; ++i)
#pragma unroll
        for (int j = 0; j < 4; ++j)
#pragma unroll
            for (int r = 0; r < 4; ++r) acc[i][j][r] = 0.f;

    const unsigned short* Ag = A + (size_t)(m0 + nl) * K + lk;
    const unsigned short* Bg = Bt + (size_t)(n0 + nl) * K + lk;

    for (int k0 = 0; k0 < K; k0 += 32) {
#pragma unroll
        for (int c = 0; c < 2; ++c) {
            const int mt = w * 2 + c;
            glds16(Ag + (size_t)mt * 16 * K + k0, &Asm[mt][0]);
            glds16(Bg + (size_t)mt * 16 * K + k0, &Bsm[mt][0]);
        }
        __syncthreads();
        bfrag af[4], bfr[4];
#pragma unroll
        for (int i = 0; i < 4; ++i) {
            af[i]  = *(const bfrag*)&Asm[wmt + i][l * 8];
            bfr[i] = *(const bfrag*)&Bsm[wnt + i][l * 8];
        }
#pragma unroll
        for (int i = 0; i < 4; ++i)
#pragma unroll
            for (int j = 0; j < 4; ++j)
                acc[i][j] = __builtin_amdgcn_mfma_f32_16x16x32_bf16(af[i], bfr[j], acc[i][j], 0, 0, 0);
        __syncthreads();
    }

    const int orow = (l >> 4) * 4, ocol = l & 15;
#pragma unroll
    for (int i = 0; i < 4; ++i) {
        const int gm = m0 + (wmt + i) * 16 + orow;
#pragma unroll
        for (int j = 0; j < 4; ++j) {
            const int gn = n0 + (wnt + j) * 16 + ocol;
            const float bs = bias[gn];
            if (VSPLIT && gn >= vstart) {
                const int vc = gn - vstart;
                const int b  = gm / Tn;
                const int tt = gm - b * Tn;
                ushort4 o;
                o.x = f2bf(acc[i][j][0] + bs);
                o.y = f2bf(acc[i][j][1] + bs);
                o.z = f2bf(acc[i][j][2] + bs);
                o.w = f2bf(acc[i][j][3] + bs);
                *(ushort4*)&vt[(size_t)(b * Hn * Dn + vc) * Tn + tt] = o;
            } else {
                const float sc = (qcols && gn < qcols) ? QSCALE : 1.f;
#pragma unroll
                for (int r = 0; r < 4; ++r) {
                    const float vv = (acc[i][j][r] + bs) * sc;
                    if (OUT_BF16)
                        ((unsigned short*)Cv)[(size_t)(gm + r) * ldc + gn] = f2bf(vv);
                    else
                        ((float*)Cv)[(size_t)(gm + r) * ldc + gn] = vv;
                }
            }
        }
    }
}

// ---------------- MFMA flash attention ----------------
// grid 512 blocks; flat id -> bh = flat&63 (XCD-local K/V), qpair = flat>>6 (0..7).
// Block handles pairs {qpair, 31-qpair} and {qpair+8, 23-qpair}: 4 q-tiles of 64,
// 34 k-tiles total -> perfectly uniform, all blocks resident in one round.
// Static-max softmax: C-init = -16 (log2 domain), no running max/rescale.
// K/V staged via glds16 into XOR-swizzled row-major tiles:
//   KT: 128 rows x 128B, chunk pos = chunk ^ (row&7)   (chunk = 16B)
//   VT:  64 rows x 256B, chunk pos = chunk ^ (row&15)
__global__ __launch_bounds__(256) void attn_mfma(
    const unsigned short* __restrict__ qkv,   // [B*T][2E]  Q|K, Q pre-scaled
    const unsigned short* __restrict__ vtg,   // [B*H*D][T] V transposed
    unsigned short* __restrict__ yattn)       // [B*T][E]
{
    __shared__ __attribute__((aligned(16))) unsigned short KT[128 * 64];
    __shared__ __attribute__((aligned(16))) unsigned short VT[64 * 128];
    __shared__ __attribute__((aligned(16))) unsigned short Ps[4][16][136];

    const int t = threadIdx.x;
    const int w = t >> 6, l = t & 63;
    const int nl = l & 15, lq = l >> 4;
    const int flat = blockIdx.x;
    const int bh = flat & 63;
    const int qp = flat >> 6;         // 0..7
    const int b = bh >> 4, h = bh & 15;

    const unsigned short* qbase = qkv + (size_t)(b * Tn) * RS2 + h * Dn;
    const unsigned short* kbase = qbase + En;
    const unsigned short* vbase = vtg + (size_t)(bh * Dn) * Tn;
    unsigned short* yb = yattn + (size_t)(b * Tn) * En + h * Dn;

#pragma unroll 1
    for (int half = 0; half < 2; ++half) {
        const int p = qp + half * 8;          // pair 0..15
#pragma unroll 1
        for (int phase = 0; phase < 2; ++phase) {
            const int qt = phase ? (31 - p) : p;
            const int rowb = qt * 64 + w * 16;
            const int jmax = qt >> 1;

            bfrag qf[2];
#pragma unroll
            for (int ks = 0; ks < 2; ++ks)
                qf[ks] = *(const bfrag*)(qbase + (size_t)(rowb + nl) * RS2 + ks * 32 + lq * 8);

            ffrag Oa[4];
            float l_i[4];
#pragma unroll
            for (int r = 0; r < 4; ++r) {
                l_i[r] = 0.f;
#pragma unroll
                for (int dt = 0; dt < 4; ++dt) Oa[dt][r] = 0.f;
            }

            for (int j = 0; j <= jmax; ++j) {
                const int k0 = j << 7;
                __syncthreads();   // prior tile's frag reads done before restage
                // K: 4 insts/wave; inst i covers rows i*8..i*8+7 (128B each, contiguous)
#pragma unroll
                for (int r = 0; r < 4; ++r) {
                    const int i = w * 4 + r;
                    glds16(kbase + (size_t)(k0 + i * 8 + (l >> 3)) * RS2 + (((l & 7) ^ (l >> 3)) << 3),
                           &KT[i * 512 + l * 8]);
                }
                // V: 4 insts/wave; inst i covers rows i*4..i*4+3 (256B each, contiguous)
#pragma unroll
                for (int r = 0; r < 4; ++r) {
                    const int i = w * 4 + r;
                    const int key = ((i & 3) << 2) + (l >> 4);
                    glds16(vbase + (size_t)(i * 4 + (l >> 4)) * Tn + k0 + (((l & 15) ^ key) << 3),
                           &VT[i * 512 + l * 8]);
                }
                __syncthreads();

                // S = Q~ K^T + (-16)  (exp2 domain, pre-scaled; static max folded in)
                ffrag s[8];
#pragma unroll
                for (int nt = 0; nt < 8; ++nt) {
                    bfrag ka = *(const bfrag*)&KT[(nt * 16 + nl) * 64 + ((((0 << 2) + lq) ^ (nl & 7)) << 3)];
                    bfrag kb = *(const bfrag*)&KT[(nt * 16 + nl) * 64 + ((((1 << 2) + lq) ^ (nl & 7)) << 3)];
                    ffrag z;
#pragma unroll
                    for (int r = 0; r < 4; ++r) z[r] = -SMAX;
                    z = __builtin_amdgcn_mfma_f32_16x16x32_bf16(qf[0], ka, z, 0, 0, 0);
                    s[nt] = __builtin_amdgcn_mfma_f32_16x16x32_bf16(qf[1], kb, s[nt] = z, 0, 0, 0);
                }

                if (j == jmax) {   // tile containing the diagonal: causal mask
#pragma unroll
                    for (int nt = 0; nt < 8; ++nt) {
                        const int kc = k0 + nt * 16 + nl;
#pragma unroll
                        for (int r = 0; r < 4; ++r)
                            if (kc > rowb + lq * 4 + r) s[nt][r] = -INFINITY;
                    }
                }

                // static-max softmax: p = exp2(s); accumulate per-lane partial l
#pragma unroll
                for (int r = 0; r < 4; ++r) {
                    const int prow = lq * 4 + r;
                    float acc = 0.f;
#pragma unroll
                    for (int nt = 0; nt < 8; ++nt) {
                        const float pvv = __builtin_amdgcn_exp2f(s[nt][r]);
                        acc += pvv;
                        Ps[w][prow][nt * 16 + nl] = f2bf_fast(pvv);
                    }
                    l_i[r] += acc;
                }

                // PV (wave-private Ps; DS pipe in-order per wave)
#pragma unroll
                for (int cs = 0; cs < 4; ++cs) {
                    bfrag pf = *(const bfrag*)&Ps[w][nl][cs * 32 + lq * 8];
#pragma unroll
                    for (int dt = 0; dt < 4; ++dt) {
                        bfrag vf = *(const bfrag*)&VT[(dt * 16 + nl) * 128 + ((((cs << 2) + lq) ^ nl) << 3)];
                        Oa[dt] = __builtin_amdgcn_mfma_f32_16x16x32_bf16(pf, vf, Oa[dt], 0, 0, 0);
                    }
                }
            }

            // epilogue: reduce l across row, normalize, store
#pragma unroll
            for (int r = 0; r < 4; ++r) {
                const float lr = rowsum16(l_i[r]);
                const float inv = 1.f / lr;
                const int row = rowb + lq * 4 + r;
#pragma unroll
                for (int dt = 0; dt < 4; ++dt)
                    yb[(size_t)row * En + dt * 16 + nl] = f2bf(Oa[dt][r] * inv);
            }
        }
    }
}

extern "C" void kernel_launch(void* const* d_in, const int* in_sizes, int n_in,
                              void* d_out, int out_size, void* d_ws, size_t ws_size,
                              hipStream_t stream)
{
    const float* x      = (const float*)d_in[0];
    const float* W_qkv  = (const float*)d_in[1];
    const float* b_qkv  = (const float*)d_in[2];
    const float* W_proj = (const float*)d_in[3];
    const float* b_proj = (const float*)d_in[4];
    float* out = (float*)d_out;

    const int M = Bn * Tn;   // 8192
    char* ws = (char*)d_ws;
    unsigned short* xb   = (unsigned short*)ws; ws += (size_t)M * En * 2;
    unsigned short* Wqt  = (unsigned short*)ws; ws += (size_t)3 * En * En * 2;
    unsigned short* Wpt  = (unsigned short*)ws; ws += (size_t)En * En * 2;
    unsigned short* qkb  = (unsigned short*)ws; ws += (size_t)M * 2 * En * 2;   // Q|K
    unsigned short* vtg  = (unsigned short*)ws; ws += (size_t)M * En * 2;       // V^T per head
    unsigned short* yb   = (unsigned short*)ws;

    f2bf_vec<<<(M * En / 4 + 255) / 256, 256, 0, stream>>>(x, xb, M * En);
    transpose_f2bf<<<dim3(3 * En / 64, En / 64), 256, 0, stream>>>(W_qkv, Wqt, En, 3 * En);
    transpose_f2bf<<<dim3(En / 64, En / 64), 256, 0, stream>>>(W_proj, Wpt, En, En);

    gemm_nt_mfma<1, 1><<<dim3(3 * En / 128, M / 128), 256, 0, stream>>>(
        xb, Wqt, b_qkv, qkb, 2 * En, vtg, 2 * En, M, 3 * En, En, En);

    attn_mfma<<<dim3(512), 256, 0, stream>>>(qkb, vtg, yb);

    gemm_nt_mfma<0, 0><<<dim3(En / 128, M / 128), 256, 0, stream>>>(
        yb, Wpt, b_proj, out, En, nullptr, 1 << 30, M, En, En, 0);
}

// Round 6
// 310.288 us; speedup vs baseline: 6.7151x; 1.0015x over previous
//
#include <hip/hip_runtime.h>
#include <math.h>

#define Bn 4
#define Tn 2048
#define En 1024
#define Hn 16
#define Dn 64
#define RS2 (2 * En)
#define QSCALE 0.18033688f   // (1/sqrt(64)) * log2(e)  -> softmax in exp2 domain
#define SMAX 16.0f           // static softmax max (log2 domain); scores bounded << 16

typedef __attribute__((ext_vector_type(8))) short bfrag;   // 8 bf16 in 4 VGPRs
typedef __attribute__((ext_vector_type(4))) float ffrag;   // 4 fp32 acc

__device__ __forceinline__ unsigned short f2bf(float f) {
    union { float f; unsigned int u; } v; v.f = f;
    unsigned int r = v.u + 0x7fffu + ((v.u >> 16) & 1u);   // RNE
    return (unsigned short)(r >> 16);
}
__device__ __forceinline__ unsigned short f2bf_fast(float f) {  // positive, no NaN
    union { float f; unsigned int u; } v; v.f = f;
    return (unsigned short)((v.u + 0x8000u) >> 16);
}

__device__ __forceinline__ void glds16(const unsigned short* g, unsigned short* l) {
    __builtin_amdgcn_global_load_lds(
        (const __attribute__((address_space(1))) unsigned int*)g,
        (__attribute__((address_space(3))) unsigned int*)l, 16, 0, 0);
}

// ---- DPP 16-lane row sum (epilogue only) ----
template <int CTRL>
__device__ __forceinline__ float dpp_add_step(float x) {
    int s = __builtin_amdgcn_update_dpp(0, __builtin_bit_cast(int, x), CTRL, 0xF, 0xF, true);
    return x + __builtin_bit_cast(float, s);
}
__device__ __forceinline__ float rowsum16(float x) {
    x = dpp_add_step<0xB1>(x);    // quad_perm xor1
    x = dpp_add_step<0x4E>(x);    // quad_perm xor2
    x = dpp_add_step<0x141>(x);   // row_half_mirror
    x = dpp_add_step<0x140>(x);   // row_mirror
    return x;
}

// ---------------- fp32 -> bf16 elementwise ----------------
__global__ __launch_bounds__(256) void f2bf_vec(const float* __restrict__ in,
                                                unsigned short* __restrict__ out, int n) {
    int i = (blockIdx.x * 256 + threadIdx.x) * 4;
    if (i >= n) return;
    float4 v = *(const float4*)(in + i);
    ushort4 o;
    o.x = f2bf(v.x); o.y = f2bf(v.y); o.z = f2bf(v.z); o.w = f2bf(v.w);
    *(ushort4*)(out + i) = o;
}

// ---------------- W[K][N] fp32 -> Wt[N][K] bf16 ----------------
__global__ __launch_bounds__(256) void transpose_f2bf(const float* __restrict__ W,
                                                      unsigned short* __restrict__ Wt,
                                                      int K, int N) {
    __shared__ float s[64][65];
    const int kt = blockIdx.y * 64, nt = blockIdx.x * 64;
    const int tx = threadIdx.x & 15, ty = threadIdx.x >> 4;
#pragma unroll
    for (int i = 0; i < 4; ++i) {
        float4 v = *(const float4*)&W[(size_t)(kt + ty + i * 16) * N + nt + tx * 4];
        s[ty + i * 16][tx * 4 + 0] = v.x;
        s[ty + i * 16][tx * 4 + 1] = v.y;
        s[ty + i * 16][tx * 4 + 2] = v.z;
        s[ty + i * 16][tx * 4 + 3] = v.w;
    }
    __syncthreads();
#pragma unroll
    for (int i = 0; i < 4; ++i) {
        const int n = ty + i * 16;
        ushort4 o;
        o.x = f2bf(s[tx * 4 + 0][n]);
        o.y = f2bf(s[tx * 4 + 1][n]);
        o.z = f2bf(s[tx * 4 + 2][n]);
        o.w = f2bf(s[tx * 4 + 3][n]);
        *(ushort4*)&Wt[(size_t)(nt + n) * K + kt + tx * 4] = o;
    }
}

// ---------------- NT bf16 MFMA GEMM, software-pipelined staging ----------------
// C = A[M,K] @ Bt[N,K]^T + bias. 128x128 tile, BK=32, 4 waves.
// Double-buffered LDS; ONE barrier per k-iter; the glds16 for iter i+1 is
// issued right after iter i's barrier, so the vmcnt(0) drain at iter i+1's
// barrier waits loads that aged a full compute phase (latency hidden).
// qcols>0: columns gn<qcols scaled by QSCALE. VSPLIT: gn>=vstart -> V^T store.
template <int OUT_BF16, int VSPLIT>
__global__ __launch_bounds__(256) void gemm_nt_mfma(
    const unsigned short* __restrict__ A, const unsigned short* __restrict__ Bt,
    const float* __restrict__ bias, void* __restrict__ Cv, int ldc,
    unsigned short* __restrict__ vt, int vstart,
    int M, int N, int K, int qcols)
{
    __shared__ __attribute__((aligned(16))) unsigned short Asm[2][8][512];
    __shared__ __attribute__((aligned(16))) unsigned short Bsm[2][8][512];

    const int t = threadIdx.x;
    const int w = t >> 6, l = t & 63;
    const int wmt = (w & 1) * 4, wnt = (w >> 1) * 4;
    const int m0 = blockIdx.y * 128, n0 = blockIdx.x * 128;
    const int nl = l & 15, lk = (l >> 4) * 8;

    ffrag acc[4][4];
#pragma unroll
    for (int i = 0; i < 4; ++i)
#pragma unroll
        for (int j = 0; j < 4; ++j)
#pragma unroll
            for (int r = 0; r < 4; ++r) acc[i][j][r] = 0.f;

    const unsigned short* Ag = A + (size_t)(m0 + nl) * K + lk;
    const unsigned short* Bg = Bt + (size_t)(n0 + nl) * K + lk;
    const int mt0 = w * 2, mt1 = w * 2 + 1;

    // prologue: stage k0=0 into buf 0
    glds16(Ag + (size_t)mt0 * 16 * K, &Asm[0][mt0][0]);
    glds16(Bg + (size_t)mt0 * 16 * K, &Bsm[0][mt0][0]);
    glds16(Ag + (size_t)mt1 * 16 * K, &Asm[0][mt1][0]);
    glds16(Bg + (size_t)mt1 * 16 * K, &Bsm[0][mt1][0]);

    const int iters = K >> 5;
#pragma unroll 1
    for (int it = 0; it < iters; ++it) {
        __syncthreads();   // drains this iter's buffer (loads aged one phase)
        const int buf = it & 1;
        if (it + 1 < iters) {
            const int nb = buf ^ 1;
            const int k1 = (it + 1) << 5;
            glds16(Ag + (size_t)mt0 * 16 * K + k1, &Asm[nb][mt0][0]);
            glds16(Bg + (size_t)mt0 * 16 * K + k1, &Bsm[nb][mt0][0]);
            glds16(Ag + (size_t)mt1 * 16 * K + k1, &Asm[nb][mt1][0]);
            glds16(Bg + (size_t)mt1 * 16 * K + k1, &Bsm[nb][mt1][0]);
        }
        bfrag af[4], bfr[4];
#pragma unroll
        for (int i = 0; i < 4; ++i) {
            af[i]  = *(const bfrag*)&Asm[buf][wmt + i][l * 8];
            bfr[i] = *(const bfrag*)&Bsm[buf][wnt + i][l * 8];
        }
#pragma unroll
        for (int i = 0; i < 4; ++i)
#pragma unroll
            for (int j = 0; j < 4; ++j)
                acc[i][j] = __builtin_amdgcn_mfma_f32_16x16x32_bf16(af[i], bfr[j], acc[i][j], 0, 0, 0);
    }

    const int orow = (l >> 4) * 4, ocol = l & 15;
#pragma unroll
    for (int i = 0; i < 4; ++i) {
        const int gm = m0 + (wmt + i) * 16 + orow;
#pragma unroll
        for (int j = 0; j < 4; ++j) {
            const int gn = n0 + (wnt + j) * 16 + ocol;
            const float bs = bias[gn];
            if (VSPLIT && gn >= vstart) {
                const int vc = gn - vstart;
                const int b  = gm / Tn;
                const int tt = gm - b * Tn;
                ushort4 o;
                o.x = f2bf(acc[i][j][0] + bs);
                o.y = f2bf(acc[i][j][1] + bs);
                o.z = f2bf(acc[i][j][2] + bs);
                o.w = f2bf(acc[i][j][3] + bs);
                *(ushort4*)&vt[(size_t)(b * Hn * Dn + vc) * Tn + tt] = o;
            } else {
                const float sc = (qcols && gn < qcols) ? QSCALE : 1.f;
#pragma unroll
                for (int r = 0; r < 4; ++r) {
                    const float vv = (acc[i][j][r] + bs) * sc;
                    if (OUT_BF16)
                        ((unsigned short*)Cv)[(size_t)(gm + r) * ldc + gn] = f2bf(vv);
                    else
                        ((float*)Cv)[(size_t)(gm + r) * ldc + gn] = vv;
                }
            }
        }
    }
}

// ---------------- MFMA flash attention (unchanged from round 5) ----------------
__global__ __launch_bounds__(256) void attn_mfma(
    const unsigned short* __restrict__ qkv,   // [B*T][2E]  Q|K, Q pre-scaled
    const unsigned short* __restrict__ vtg,   // [B*H*D][T] V transposed
    unsigned short* __restrict__ yattn)       // [B*T][E]
{
    __shared__ __attribute__((aligned(16))) unsigned short KT[128 * 64];
    __shared__ __attribute__((aligned(16))) unsigned short VT[64 * 128];
    __shared__ __attribute__((aligned(16))) unsigned short Ps[4][16][136];

    const int t = threadIdx.x;
    const int w = t >> 6, l = t & 63;
    const int nl = l & 15, lq = l >> 4;
    const int flat = blockIdx.x;
    const int bh = flat & 63;
    const int qp = flat >> 6;         // 0..7
    const int b = bh >> 4, h = bh & 15;

    const unsigned short* qbase = qkv + (size_t)(b * Tn) * RS2 + h * Dn;
    const unsigned short* kbase = qbase + En;
    const unsigned short* vbase = vtg + (size_t)(bh * Dn) * Tn;
    unsigned short* yb = yattn + (size_t)(b * Tn) * En + h * Dn;

#pragma unroll 1
    for (int half = 0; half < 2; ++half) {
        const int p = qp + half * 8;          // pair 0..15
#pragma unroll 1
        for (int phase = 0; phase < 2; ++phase) {
            const int qt = phase ? (31 - p) : p;
            const int rowb = qt * 64 + w * 16;
            const int jmax = qt >> 1;

            bfrag qf[2];
#pragma unroll
            for (int ks = 0; ks < 2; ++ks)
                qf[ks] = *(const bfrag*)(qbase + (size_t)(rowb + nl) * RS2 + ks * 32 + lq * 8);

            ffrag Oa[4];
            float l_i[4];
#pragma unroll
            for (int r = 0; r < 4; ++r) {
                l_i[r] = 0.f;
#pragma unroll
                for (int dt = 0; dt < 4; ++dt) Oa[dt][r] = 0.f;
            }

            for (int j = 0; j <= jmax; ++j) {
                const int k0 = j << 7;
                __syncthreads();   // prior tile's frag reads done before restage
#pragma unroll
                for (int r = 0; r < 4; ++r) {
                    const int i = w * 4 + r;
                    glds16(kbase + (size_t)(k0 + i * 8 + (l >> 3)) * RS2 + (((l & 7) ^ (l >> 3)) << 3),
                           &KT[i * 512 + l * 8]);
                }
#pragma unroll
                for (int r = 0; r < 4; ++r) {
                    const int i = w * 4 + r;
                    const int key = ((i & 3) << 2) + (l >> 4);
                    glds16(vbase + (size_t)(i * 4 + (l >> 4)) * Tn + k0 + (((l & 15) ^ key) << 3),
                           &VT[i * 512 + l * 8]);
                }
                __syncthreads();

                // S = Q~ K^T + (-16)  (exp2 domain, pre-scaled; static max folded in)
                ffrag s[8];
#pragma unroll
                for (int nt = 0; nt < 8; ++nt) {
                    bfrag ka = *(const bfrag*)&KT[(nt * 16 + nl) * 64 + (((lq) ^ (nl & 7)) << 3)];
                    bfrag kb = *(const bfrag*)&KT[(nt * 16 + nl) * 64 + (((4 + lq) ^ (nl & 7)) << 3)];
                    ffrag z;
#pragma unroll
                    for (int r = 0; r < 4; ++r) z[r] = -SMAX;
                    z = __builtin_amdgcn_mfma_f32_16x16x32_bf16(qf[0], ka, z, 0, 0, 0);
                    s[nt] = __builtin_amdgcn_mfma_f32_16x16x32_bf16(qf[1], kb, z, 0, 0, 0);
                }

                if (j == jmax) {   // tile containing the diagonal: causal mask
#pragma unroll
                    for (int nt = 0; nt < 8; ++nt) {
                        const int kc = k0 + nt * 16 + nl;
#pragma unroll
                        for (int r = 0; r < 4; ++r)
                            if (kc > rowb + lq * 4 + r) s[nt][r] = -INFINITY;
                    }
                }

                // static-max softmax: p = exp2(s); per-lane partial row sums
#pragma unroll
                for (int r = 0; r < 4; ++r) {
                    const int prow = lq * 4 + r;
                    float acc = 0.f;
#pragma unroll
                    for (int nt = 0; nt < 8; ++nt) {
                        const float pvv = __builtin_amdgcn_exp2f(s[nt][r]);
                        acc += pvv;
                        Ps[w][prow][nt * 16 + nl] = f2bf_fast(pvv);
                    }
                    l_i[r] += acc;
                }

                // PV (wave-private Ps; DS pipe in-order per wave)
#pragma unroll
                for (int cs = 0; cs < 4; ++cs) {
                    bfrag pf = *(const bfrag*)&Ps[w][nl][cs * 32 + lq * 8];
#pragma unroll
                    for (int dt = 0; dt < 4; ++dt) {
                        bfrag vf = *(const bfrag*)&VT[(dt * 16 + nl) * 128 + ((((cs << 2) + lq) ^ nl) << 3)];
                        Oa[dt] = __builtin_amdgcn_mfma_f32_16x16x32_bf16(pf, vf, Oa[dt], 0, 0, 0);
                    }
                }
            }

            // epilogue: reduce l across row, normalize, store
#pragma unroll
            for (int r = 0; r < 4; ++r) {
                const float lr = rowsum16(l_i[r]);
                const float inv = 1.f / lr;
                const int row = rowb + lq * 4 + r;
#pragma unroll
                for (int dt = 0; dt < 4; ++dt)
                    yb[(size_t)row * En + dt * 16 + nl] = f2bf(Oa[dt][r] * inv);
            }
        }
    }
}

extern "C" void kernel_launch(void* const* d_in, const int* in_sizes, int n_in,
                              void* d_out, int out_size, void* d_ws, size_t ws_size,
                              hipStream_t stream)
{
    const float* x      = (const float*)d_in[0];
    const float* W_qkv  = (const float*)d_in[1];
    const float* b_qkv  = (const float*)d_in[2];
    const float* W_proj = (const float*)d_in[3];
    const float* b_proj = (const float*)d_in[4];
    float* out = (float*)d_out;

    const int M = Bn * Tn;   // 8192
    char* ws = (char*)d_ws;
    unsigned short* xb   = (unsigned short*)ws; ws += (size_t)M * En * 2;
    unsigned short* Wqt  = (unsigned short*)ws; ws += (size_t)3 * En * En * 2;
    unsigned short* Wpt  = (unsigned short*)ws; ws += (size_t)En * En * 2;
    unsigned short* qkb  = (unsigned short*)ws; ws += (size_t)M * 2 * En * 2;   // Q|K
    unsigned short* vtg  = (unsigned short*)ws; ws += (size_t)M * En * 2;       // V^T per head
    unsigned short* yb   = (unsigned short*)ws;

    f2bf_vec<<<(M * En / 4 + 255) / 256, 256, 0, stream>>>(x, xb, M * En);
    transpose_f2bf<<<dim3(3 * En / 64, En / 64), 256, 0, stream>>>(W_qkv, Wqt, En, 3 * En);
    transpose_f2bf<<<dim3(En / 64, En / 64), 256, 0, stream>>>(W_proj, Wpt, En, En);

    gemm_nt_mfma<1, 1><<<dim3(3 * En / 128, M / 128), 256, 0, stream>>>(
        xb, Wqt, b_qkv, qkb, 2 * En, vtg, 2 * En, M, 3 * En, En, En);

    attn_mfma<<<dim3(512), 256, 0, stream>>>(qkb, vtg, yb);

    gemm_nt_mfma<0, 0><<<dim3(En / 128, M / 128), 256, 0, stream>>>(
        yb, Wpt, b_proj, out, En, nullptr, 1 << 30, M, En, En, 0);
}